// Round 1
// baseline (772.091 us; speedup 1.0000x reference)
//
#include <hip/hip_runtime.h>
#include <math.h>

#define NB 8
#define NN 8192
#define ND 1024
#define NH 256
#define NC 2
#define ROWS 16
#define NSPLIT 32

__device__ inline float wave_reduce_sum(float v) {
#pragma unroll
    for (int off = 32; off > 0; off >>= 1)
        v += __shfl_down(v, off, 64);
    return v;
}
__device__ inline float wave_reduce_max(float v) {
#pragma unroll
    for (int off = 32; off > 0; off >>= 1)
        v = fmaxf(v, __shfl_down(v, off, 64));
    return v;
}

// Kernel 1: h = silu(x @ Wp + bp); a = h @ Wa + ba
// block = 256 threads, handles 16 rows of one bag.
// thread layout: cg = tid&127 -> columns {cg, cg+128}; rg = tid>>7 -> rows {rg*8..rg*8+7}
__global__ __launch_bounds__(256, 2)
void proj_kernel(const float* __restrict__ x, const float* __restrict__ Wp,
                 const float* __restrict__ bp, const float* __restrict__ Wa,
                 const float* __restrict__ ba,
                 float* __restrict__ h_out, float* __restrict__ a_out)
{
    __shared__ float xs[ROWS][ND];      // 64 KB
    __shared__ float redbuf[4][8];      // per-wave partial a

    const int b  = blockIdx.y;
    const int n0 = blockIdx.x * ROWS;

    // cooperative load: 16 rows x 1024 f32 = 64 KB, fully coalesced float4
    const float4* xv  = (const float4*)(x + ((size_t)b * NN + n0) * ND);
    float4*       xsv = (float4*)&xs[0][0];
#pragma unroll
    for (int i = 0; i < (ROWS * ND / 4) / 256; ++i)
        xsv[threadIdx.x + i * 256] = xv[threadIdx.x + i * 256];
    __syncthreads();

    const int cg = threadIdx.x & 127;
    const int rg = threadIdx.x >> 7;
    const int c0 = cg, c1 = cg + 128;
    const int r0 = rg * 8;

    float acc0[8] = {0.f,0.f,0.f,0.f,0.f,0.f,0.f,0.f};
    float acc1[8] = {0.f,0.f,0.f,0.f,0.f,0.f,0.f,0.f};

    for (int d = 0; d < ND; d += 4) {
        float w0[4], w1[4];
#pragma unroll
        for (int k = 0; k < 4; ++k) {
            w0[k] = Wp[(size_t)(d + k) * NH + c0];
            w1[k] = Wp[(size_t)(d + k) * NH + c1];
        }
#pragma unroll
        for (int r = 0; r < 8; ++r) {
            float4 xr = *(const float4*)&xs[r0 + r][d];   // LDS broadcast per wave
            acc0[r] = fmaf(xr.x, w0[0], acc0[r]);
            acc0[r] = fmaf(xr.y, w0[1], acc0[r]);
            acc0[r] = fmaf(xr.z, w0[2], acc0[r]);
            acc0[r] = fmaf(xr.w, w0[3], acc0[r]);
            acc1[r] = fmaf(xr.x, w1[0], acc1[r]);
            acc1[r] = fmaf(xr.y, w1[1], acc1[r]);
            acc1[r] = fmaf(xr.z, w1[2], acc1[r]);
            acc1[r] = fmaf(xr.w, w1[3], acc1[r]);
        }
    }

    const float bp0 = bp[c0], bp1 = bp[c1];
    const float wa0 = Wa[c0], wa1 = Wa[c1];
    const int wave = threadIdx.x >> 6;
    const int lane = threadIdx.x & 63;

#pragma unroll
    for (int r = 0; r < 8; ++r) {
        float v0 = acc0[r] + bp0;
        float v1 = acc1[r] + bp1;
        float h0 = v0 / (1.f + expf(-v0));   // silu
        float h1 = v1 / (1.f + expf(-v1));
        size_t row = (size_t)b * NN + n0 + r0 + r;
        h_out[row * NH + c0] = h0;
        h_out[row * NH + c1] = h1;
        float pa = h0 * wa0 + h1 * wa1;
        pa = wave_reduce_sum(pa);
        if (lane == 0) redbuf[wave][r] = pa;
    }
    __syncthreads();
    // waves {0,1} hold rows 0..7, waves {2,3} rows 8..15
    if (threadIdx.x < 16) {
        int rr = threadIdx.x & 7;
        int g  = threadIdx.x >> 3;
        float av = redbuf[g * 2][rr] + redbuf[g * 2 + 1][rr] + ba[0];
        a_out[(size_t)b * NN + n0 + g * 8 + rr] = av;
    }
}

// Kernel 2: per-bag masked softmax stats (max + sum of exp)
__global__ void stats_kernel(const float* __restrict__ a, const int* __restrict__ lengths,
                             float* __restrict__ ms)
{
    __shared__ float red[4];
    __shared__ float bcast;
    const int b   = blockIdx.x;
    const int len = lengths[b];
    const float* ab = a + (size_t)b * NN;
    const int wave = threadIdx.x >> 6, lane = threadIdx.x & 63;

    float m = -1e30f;
    for (int n = threadIdx.x; n < len; n += 256)
        m = fmaxf(m, ab[n]);
    m = wave_reduce_max(m);
    if (lane == 0) red[wave] = m;
    __syncthreads();
    if (threadIdx.x == 0)
        bcast = fmaxf(fmaxf(red[0], red[1]), fmaxf(red[2], red[3]));
    __syncthreads();
    m = bcast;

    float s = 0.f;
    for (int n = threadIdx.x; n < len; n += 256)
        s += expf(ab[n] - m);
    s = wave_reduce_sum(s);
    if (lane == 0) red[wave] = s;
    __syncthreads();
    if (threadIdx.x == 0) {
        ms[b * 2]     = m;
        ms[b * 2 + 1] = red[0] + red[1] + red[2] + red[3];
    }
}

// Kernel 3: partial pooled[b, split, c] = sum_n p[n] * h[n, c]
__global__ __launch_bounds__(256)
void pool_kernel(const float* __restrict__ h, const float* __restrict__ a,
                 const int* __restrict__ lengths, const float* __restrict__ ms,
                 float* __restrict__ part)
{
    const int b = blockIdx.y;
    const int s = blockIdx.x;
    const int len = lengths[b];
    const float m     = ms[b * 2];
    const float inv_s = 1.f / ms[b * 2 + 1];

    int nbeg = s * (NN / NSPLIT);
    int nend = nbeg + (NN / NSPLIT);
    if (nend > len) nend = len;

    const float* ab = a + (size_t)b * NN;
    const float* hb = h + ((size_t)b * NN) * NH + threadIdx.x;

    float acc = 0.f;
    for (int n = nbeg; n < nend; ++n) {
        float p = expf(ab[n] - m);                 // uniform across threads
        acc = fmaf(p, hb[(size_t)n * NH], acc);    // coalesced 1 KB/row
    }
    part[((size_t)b * NSPLIT + s) * NH + threadIdx.x] = acc * inv_s;
}

// Kernel 4: pooled = sum of partials; logits = pooled @ Wc + bc
__global__ void final_kernel(const float* __restrict__ part, const float* __restrict__ Wc,
                             const float* __restrict__ bc, float* __restrict__ out)
{
    __shared__ float red0[4], red1[4];
    const int c = threadIdx.x;
    const float wc0 = Wc[c * NC + 0], wc1 = Wc[c * NC + 1];
    const int wave = threadIdx.x >> 6, lane = threadIdx.x & 63;

    for (int b = 0; b < NB; ++b) {
        float pooled = 0.f;
#pragma unroll 4
        for (int s = 0; s < NSPLIT; ++s)
            pooled += part[((size_t)b * NSPLIT + s) * NH + c];
        float l0 = pooled * wc0;
        float l1 = pooled * wc1;
        l0 = wave_reduce_sum(l0);
        l1 = wave_reduce_sum(l1);
        if (lane == 0) { red0[wave] = l0; red1[wave] = l1; }
        __syncthreads();
        if (threadIdx.x == 0) {
            out[b * NC + 0] = red0[0] + red0[1] + red0[2] + red0[3] + bc[0];
            out[b * NC + 1] = red1[0] + red1[1] + red1[2] + red1[3] + bc[1];
        }
        __syncthreads();
    }
}

extern "C" void kernel_launch(void* const* d_in, const int* in_sizes, int n_in,
                              void* d_out, int out_size, void* d_ws, size_t ws_size,
                              hipStream_t stream)
{
    const float* x       = (const float*)d_in[0];
    const int*   lengths = (const int*)d_in[1];
    const float* Wp      = (const float*)d_in[2];
    const float* bp      = (const float*)d_in[3];
    const float* Wa      = (const float*)d_in[4];
    const float* ba      = (const float*)d_in[5];
    const float* Wc      = (const float*)d_in[6];
    const float* bc      = (const float*)d_in[7];
    float* out = (float*)d_out;

    // workspace layout (fp32):
    float* h_buf  = (float*)d_ws;                       // B*N*H  = 16,777,216 f
    float* a_buf  = h_buf + (size_t)NB * NN * NH;       // B*N    = 65,536 f
    float* ms_buf = a_buf + (size_t)NB * NN;            // 2*B    = 16 f
    float* part   = ms_buf + 2 * NB;                    // B*32*H = 65,536 f
    // total ~64.5 MiB

    dim3 g1(NN / ROWS, NB);   // 512 x 8 blocks
    proj_kernel<<<g1, 256, 0, stream>>>(x, Wp, bp, Wa, ba, h_buf, a_buf);
    stats_kernel<<<NB, 256, 0, stream>>>(a_buf, lengths, ms_buf);
    dim3 g3(NSPLIT, NB);      // 32 x 8 blocks
    pool_kernel<<<g3, 256, 0, stream>>>(h_buf, a_buf, lengths, ms_buf, part);
    final_kernel<<<1, 256, 0, stream>>>(part, Wc, bc, out);
}

// Round 2
// 217.188 us; speedup vs baseline: 3.5549x; 3.5549x over previous
//
#include <hip/hip_runtime.h>
#include <math.h>

#define NB 8
#define NN 8192
#define ND 1024
#define NH 256
#define NC 2
#define NSPLIT 32
#define M_ALL (NB * NN)   // 65536 rows total

typedef __attribute__((ext_vector_type(8))) short bf16x8;
typedef __attribute__((ext_vector_type(4))) float f32x4;

__device__ inline unsigned short f2bf(float f) {   // RNE float -> bf16 bits
    unsigned int u = __builtin_bit_cast(unsigned int, f);
    u += 0x7FFFu + ((u >> 16) & 1u);
    return (unsigned short)(u >> 16);
}
__device__ inline float bf2f(unsigned short s) {
    unsigned int u = ((unsigned int)s) << 16;
    return __builtin_bit_cast(float, u);
}

__device__ inline float wave_reduce_sum(float v) {
#pragma unroll
    for (int off = 32; off > 0; off >>= 1) v += __shfl_down(v, off, 64);
    return v;
}
__device__ inline float wave_reduce_max(float v) {
#pragma unroll
    for (int off = 32; off > 0; off >>= 1) v = fmaxf(v, __shfl_down(v, off, 64));
    return v;
}

// ---------------------------------------------------------------------------
// Pack Wp into bf16 hi/lo, MFMA-B-fragment-contiguous:
// frag (t = k-step 0..31, f = col-frag 0..15), lane l holds
// B[k = t*32 + (l>>4)*8 + j][col = f*16 + (l&15)], j=0..7 contiguous.
// offset = ((t*16 + f)*64 + l)*8
// ---------------------------------------------------------------------------
__global__ void pack_kernel(const float* __restrict__ Wp,
                            unsigned short* __restrict__ hi,
                            unsigned short* __restrict__ lo)
{
    int idx  = blockIdx.x * 256 + threadIdx.x;   // 0..32767
    int lane = idx & 63;
    int f    = (idx >> 6) & 15;
    int t    = idx >> 10;
    int col  = f * 16 + (lane & 15);
    int k0   = t * 32 + (lane >> 4) * 8;
    size_t off = (size_t)idx * 8;
#pragma unroll
    for (int j = 0; j < 8; ++j) {
        float w = Wp[(size_t)(k0 + j) * NH + col];
        unsigned short h = f2bf(w);
        hi[off + j] = h;
        lo[off + j] = f2bf(w - bf2f(h));
    }
}

// ---------------------------------------------------------------------------
// GEMM: h = silu(x @ Wp + bp), h stored bf16.
// Block: 256 thr = 4 waves, tile 64 rows x 256 cols (full N -> x read once).
// K loop: BK=64, double-buffered LDS for x (bf16, XOR-swizzled), B frags
// loaded straight from L2-resident packed hi/lo.
// ---------------------------------------------------------------------------
__global__ __launch_bounds__(256, 2)
void gemm_kernel(const float* __restrict__ x,
                 const unsigned short* __restrict__ Bhi,
                 const unsigned short* __restrict__ Blo,
                 const float* __restrict__ bp,
                 unsigned short* __restrict__ h_out)
{
    __shared__ unsigned short As[2][64 * 64];   // 2 x 8 KB, bf16, swizzled

    const int tid  = threadIdx.x;
    const int wave = tid >> 6;
    const int lane = tid & 63;
    const size_t row0 = (size_t)blockIdx.x * 64;

    // staging: thread handles row = tid/4, k-chunk = (tid%4)*16 (16 elems)
    const int srow = tid >> 2;
    const int sk   = (tid & 3) * 16;
    const float* xp = x + (row0 + srow) * ND + sk;
    const int by0 = (sk * 2) ^ ((srow & 7) << 4);   // swizzled byte-in-row
    char* rowp0 = (char*)&As[0][srow * 64];
    char* rowp1 = (char*)&As[1][srow * 64];

    float4 g[4];
    auto loadregs = [&](int t) {
        const float4* p = (const float4*)(xp + t * 64);
        g[0] = p[0]; g[1] = p[1]; g[2] = p[2]; g[3] = p[3];
    };
    auto dswrite = [&](int buf) {
        unsigned short u[16];
#pragma unroll
        for (int i = 0; i < 4; ++i) {
            u[i * 4 + 0] = f2bf(g[i].x);
            u[i * 4 + 1] = f2bf(g[i].y);
            u[i * 4 + 2] = f2bf(g[i].z);
            u[i * 4 + 3] = f2bf(g[i].w);
        }
        bf16x8 w0, w1;
#pragma unroll
        for (int i = 0; i < 8; ++i) { w0[i] = (short)u[i]; w1[i] = (short)u[8 + i]; }
        char* rp = buf ? rowp1 : rowp0;
        *(bf16x8*)(rp + by0)        = w0;
        *(bf16x8*)(rp + (by0 ^ 16)) = w1;
    };

    f32x4 acc[4][4];
#pragma unroll
    for (int m = 0; m < 4; ++m)
#pragma unroll
        for (int n = 0; n < 4; ++n) acc[m][n] = f32x4{0.f, 0.f, 0.f, 0.f};

    // per-wave B base: frags f = wave*4 + n
    const unsigned short* bhp = Bhi + ((size_t)(wave * 4) * 64 + lane) * 8;
    const unsigned short* blp = Blo + ((size_t)(wave * 4) * 64 + lane) * 8;

    auto compute = [&](int buf, int t) {
#pragma unroll
        for (int tk = 0; tk < 2; ++tk) {
            const int kk = t * 2 + tk;
            bf16x8 afr[4];
#pragma unroll
            for (int m = 0; m < 4; ++m) {
                int arow = m * 16 + (lane & 15);
                int byr  = (tk * 64 + (lane >> 4) * 16) ^ ((arow & 7) << 4);
                afr[m] = *(const bf16x8*)((const char*)&As[buf][arow * 64] + byr);
            }
            bf16x8 bh[4], bl[4];
#pragma unroll
            for (int n = 0; n < 4; ++n) {
                size_t bo = (size_t)(kk * 16 + n) * 512;   // (kk*16+n)*64*8
                bh[n] = *(const bf16x8*)(bhp + bo);
                bl[n] = *(const bf16x8*)(blp + bo);
            }
#pragma unroll
            for (int m = 0; m < 4; ++m)
#pragma unroll
                for (int n = 0; n < 4; ++n) {
                    acc[m][n] = __builtin_amdgcn_mfma_f32_16x16x32_bf16(afr[m], bh[n], acc[m][n], 0, 0, 0);
                    acc[m][n] = __builtin_amdgcn_mfma_f32_16x16x32_bf16(afr[m], bl[n], acc[m][n], 0, 0, 0);
                }
        }
    };

    loadregs(0);
    dswrite(0);
    loadregs(1);
    __syncthreads();

    for (int t = 0; t < 16; ++t) {
        compute(t & 1, t);
        if (t < 15) {
            dswrite((t + 1) & 1);
            if (t + 2 < 16) loadregs(t + 2);
        }
        __syncthreads();
    }

    // epilogue: bias + SiLU, store h as bf16
#pragma unroll
    for (int n = 0; n < 4; ++n) {
        int col = wave * 64 + n * 16 + (lane & 15);
        float bpc = bp[col];
#pragma unroll
        for (int m = 0; m < 4; ++m) {
            size_t rowb = row0 + m * 16 + ((lane >> 4) * 4);
#pragma unroll
            for (int j = 0; j < 4; ++j) {
                float v  = acc[m][n][j] + bpc;
                float hh = v / (1.f + __expf(-v));
                h_out[(rowb + j) * NH + col] = f2bf(hh);
            }
        }
    }
}

// ---------------------------------------------------------------------------
// a = h @ Wa + ba  (GEMV over bf16 h). One wave per row, 32 rows/wave.
// ---------------------------------------------------------------------------
__global__ __launch_bounds__(256)
void a_kernel(const unsigned short* __restrict__ h, const float* __restrict__ Wa,
              const float* __restrict__ ba, float* __restrict__ a_out)
{
    const int wave = threadIdx.x >> 6, lane = threadIdx.x & 63;
    const float4 wv = *(const float4*)(Wa + lane * 4);
    const float ba0 = ba[0];
    const int base = blockIdx.x * 128 + wave * 32;
    for (int r = 0; r < 32; ++r) {
        size_t row = (size_t)base + r;
        const ushort4 hv = *(const ushort4*)(h + row * NH + lane * 4);
        float s = bf2f(hv.x) * wv.x + bf2f(hv.y) * wv.y +
                  bf2f(hv.z) * wv.z + bf2f(hv.w) * wv.w;
        s = wave_reduce_sum(s);
        if (lane == 0) a_out[row] = s + ba0;
    }
}

// ---------------------------------------------------------------------------
// per-bag masked softmax stats (max, sumexp)
// ---------------------------------------------------------------------------
__global__ void stats_kernel(const float* __restrict__ a, const int* __restrict__ lengths,
                             float* __restrict__ ms)
{
    __shared__ float red[4];
    __shared__ float bcast;
    const int b   = blockIdx.x;
    const int len = lengths[b];
    const float* ab = a + (size_t)b * NN;
    const int wave = threadIdx.x >> 6, lane = threadIdx.x & 63;

    float m = -1e30f;
    for (int n = threadIdx.x; n < len; n += 256) m = fmaxf(m, ab[n]);
    m = wave_reduce_max(m);
    if (lane == 0) red[wave] = m;
    __syncthreads();
    if (threadIdx.x == 0) bcast = fmaxf(fmaxf(red[0], red[1]), fmaxf(red[2], red[3]));
    __syncthreads();
    m = bcast;

    float s = 0.f;
    for (int n = threadIdx.x; n < len; n += 256) s += expf(ab[n] - m);
    s = wave_reduce_sum(s);
    if (lane == 0) red[wave] = s;
    __syncthreads();
    if (threadIdx.x == 0) {
        ms[b * 2]     = m;
        ms[b * 2 + 1] = red[0] + red[1] + red[2] + red[3];
    }
}

// ---------------------------------------------------------------------------
// partial pooled[b, split, c] = sum_n p[n] * h[n, c]
// ---------------------------------------------------------------------------
__global__ __launch_bounds__(256)
void pool_kernel(const unsigned short* __restrict__ h, const float* __restrict__ a,
                 const int* __restrict__ lengths, const float* __restrict__ ms,
                 float* __restrict__ part)
{
    const int b = blockIdx.y;
    const int s = blockIdx.x;
    const int len = lengths[b];
    const float m     = ms[b * 2];
    const float inv_s = 1.f / ms[b * 2 + 1];

    int nbeg = s * (NN / NSPLIT);
    int nend = nbeg + (NN / NSPLIT);
    if (nend > len) nend = len;

    const float* ab = a + (size_t)b * NN;
    const unsigned short* hb = h + ((size_t)b * NN) * NH + threadIdx.x;

    float acc = 0.f;
    for (int n = nbeg; n < nend; ++n) {
        float p = expf(ab[n] - m);
        acc = fmaf(p, bf2f(hb[(size_t)n * NH]), acc);
    }
    part[((size_t)b * NSPLIT + s) * NH + threadIdx.x] = acc * inv_s;
}

// ---------------------------------------------------------------------------
// pooled = sum partials; logits = pooled @ Wc + bc
// ---------------------------------------------------------------------------
__global__ void final_kernel(const float* __restrict__ part, const float* __restrict__ Wc,
                             const float* __restrict__ bc, float* __restrict__ out)
{
    __shared__ float red0[4], red1[4];
    const int c = threadIdx.x;
    const float wc0 = Wc[c * NC + 0], wc1 = Wc[c * NC + 1];
    const int wave = threadIdx.x >> 6, lane = threadIdx.x & 63;

    for (int b = 0; b < NB; ++b) {
        float pooled = 0.f;
#pragma unroll 4
        for (int s = 0; s < NSPLIT; ++s)
            pooled += part[((size_t)b * NSPLIT + s) * NH + c];
        float l0 = pooled * wc0;
        float l1 = pooled * wc1;
        l0 = wave_reduce_sum(l0);
        l1 = wave_reduce_sum(l1);
        if (lane == 0) { red0[wave] = l0; red1[wave] = l1; }
        __syncthreads();
        if (threadIdx.x == 0) {
            out[b * NC + 0] = red0[0] + red0[1] + red0[2] + red0[3] + bc[0];
            out[b * NC + 1] = red1[0] + red1[1] + red1[2] + red1[3] + bc[1];
        }
        __syncthreads();
    }
}

extern "C" void kernel_launch(void* const* d_in, const int* in_sizes, int n_in,
                              void* d_out, int out_size, void* d_ws, size_t ws_size,
                              hipStream_t stream)
{
    const float* x       = (const float*)d_in[0];
    const int*   lengths = (const int*)d_in[1];
    const float* Wp      = (const float*)d_in[2];
    const float* bp      = (const float*)d_in[3];
    const float* Wa      = (const float*)d_in[4];
    const float* ba      = (const float*)d_in[5];
    const float* Wc      = (const float*)d_in[6];
    const float* bc      = (const float*)d_in[7];
    float* out = (float*)d_out;

    // workspace layout
    unsigned short* whi   = (unsigned short*)d_ws;            // 262144 bf16 (512 KB)
    unsigned short* wlo   = whi + 262144;                     // 512 KB
    unsigned short* h_buf = wlo + 262144;                     // 16.7M bf16 (32 MB)
    float* a_buf  = (float*)(h_buf + (size_t)M_ALL * NH);     // 256 KB
    float* ms_buf = a_buf + M_ALL;                            // 64 B
    float* part   = ms_buf + 2 * NB;                          // 256 KB

    pack_kernel<<<128, 256, 0, stream>>>(Wp, whi, wlo);
    gemm_kernel<<<M_ALL / 64, 256, 0, stream>>>(x, whi, wlo, bp, h_buf);
    a_kernel<<<M_ALL / 128, 256, 0, stream>>>(h_buf, Wa, ba, a_buf);
    stats_kernel<<<NB, 256, 0, stream>>>(a_buf, lengths, ms_buf);
    pool_kernel<<<dim3(NSPLIT, NB), 256, 0, stream>>>(h_buf, a_buf, lengths, ms_buf, part);
    final_kernel<<<1, 256, 0, stream>>>(part, Wc, bc, out);
}

// Round 4
// 149.690 us; speedup vs baseline: 5.1579x; 1.4509x over previous
//
#include <hip/hip_runtime.h>
#include <math.h>

#define NB 8
#define NN 8192
#define ND 1024
#define NH 256
#define NC 2
#define NSPLIT 64
#define M_ALL (NB * NN)   // 65536 rows
#define BK 32
#define NT (ND / BK)      // 32 K-steps
#define AROW 40           // ushorts per LDS row (80 B stride: 2-way max bank aliasing)

typedef __attribute__((ext_vector_type(8))) short bf16x8;
typedef __attribute__((ext_vector_type(4))) float f32x4;

// barrier WITHOUT the compiler's vmcnt(0) drain: LDS ordering only.
#define BARRIER_LGKM() asm volatile("s_waitcnt lgkmcnt(0)\n\ts_barrier" ::: "memory")

__device__ inline unsigned short f2bf(float f) {   // RNE float -> bf16 bits
    unsigned int u = __builtin_bit_cast(unsigned int, f);
    u += 0x7FFFu + ((u >> 16) & 1u);
    return (unsigned short)(u >> 16);
}
__device__ inline float bf2f(unsigned short s) {
    unsigned int u = ((unsigned int)s) << 16;
    return __builtin_bit_cast(float, u);
}
__device__ inline unsigned int pk_bf16(float a, float b) {  // low=a, high=b
    return (unsigned int)f2bf(a) | ((unsigned int)f2bf(b) << 16);
}

__device__ inline float wave_reduce_sum(float v) {
#pragma unroll
    for (int off = 32; off > 0; off >>= 1) v += __shfl_down(v, off, 64);
    return v;
}
__device__ inline float wave_reduce_max(float v) {
#pragma unroll
    for (int off = 32; off > 0; off >>= 1) v = fmaxf(v, __shfl_down(v, off, 64));
    return v;
}

// ---------------------------------------------------------------------------
// Pack Wp into bf16 hi/lo, MFMA-B-fragment-contiguous:
// frag (t = k-step 0..31, f = col-frag 0..15), lane l holds
// B[k = t*32 + (l>>4)*8 + j][col = f*16 + (l&15)], j=0..7 contiguous.
// ---------------------------------------------------------------------------
__global__ void pack_kernel(const float* __restrict__ Wp,
                            unsigned short* __restrict__ hi,
                            unsigned short* __restrict__ lo)
{
    int idx  = blockIdx.x * 256 + threadIdx.x;   // 0..32767
    int lane = idx & 63;
    int f    = (idx >> 6) & 15;
    int t    = idx >> 10;
    int col  = f * 16 + (lane & 15);
    int k0   = t * 32 + (lane >> 4) * 8;
    size_t off = (size_t)idx * 8;
#pragma unroll
    for (int j = 0; j < 8; ++j) {
        float w = Wp[(size_t)(k0 + j) * NH + col];
        unsigned short h = f2bf(w);
        hi[off + j] = h;
        lo[off + j] = f2bf(w - bf2f(h));
    }
}

// ---------------------------------------------------------------------------
// GEMM: h = silu(x @ Wp + bp) stored bf16; fused a = h @ Wa + ba.
// Block 256 thr / 4 waves, tile 64 rows x 256 cols, BK=32, double-buffered
// LDS for x(bf16), lgkm-only barriers so global prefetch stays in flight.
// ---------------------------------------------------------------------------
__global__ __launch_bounds__(256, 3)
void gemm_kernel(const float* __restrict__ x,
                 const unsigned short* __restrict__ Bhi,
                 const unsigned short* __restrict__ Blo,
                 const float* __restrict__ bp,
                 const float* __restrict__ Wa,
                 const float* __restrict__ ba,
                 unsigned short* __restrict__ h_out,
                 float* __restrict__ a_out)
{
    __shared__ __align__(16) unsigned short As[2][64 * AROW];  // 2 x 5 KB
    __shared__ float a_red[4][64];

    const int tid  = threadIdx.x;
    const int wave = tid >> 6;
    const int lane = tid & 63;
    const size_t row0 = (size_t)blockIdx.x * 64;

    // staging: thread -> row srow, k-slot slot (8 fp32)
    const int srow = tid >> 2;
    const int slot = tid & 3;
    const float* xp = x + (row0 + srow) * ND + slot * 8;
    unsigned short* const wp0 = &As[0][srow * AROW + slot * 8];
    unsigned short* const wp1 = &As[1][srow * AROW + slot * 8];

    float4 ga, gb;
    auto dswrite = [&](int buf) {
        uint4 w;
        w.x = pk_bf16(ga.x, ga.y);
        w.y = pk_bf16(ga.z, ga.w);
        w.z = pk_bf16(gb.x, gb.y);
        w.w = pk_bf16(gb.z, gb.w);
        *(uint4*)(buf ? wp1 : wp0) = w;
    };

    f32x4 acc[4][4];
#pragma unroll
    for (int m = 0; m < 4; ++m)
#pragma unroll
        for (int n = 0; n < 4; ++n) acc[m][n] = f32x4{0.f, 0.f, 0.f, 0.f};

    // prologue: tile0 -> LDS buf0, tile1 in regs, barrier (x loads survive)
    { const float4* p = (const float4*)xp;        ga = p[0]; gb = p[1]; }
    dswrite(0);
    { const float4* p = (const float4*)(xp + BK); ga = p[0]; gb = p[1]; }
    BARRIER_LGKM();

    for (int t = 0; t < NT; ++t) {
        const int cur = t & 1;
        // 1) stage tile t+1 (regs loaded at t-1) into the other buffer
        if (t < NT - 1) dswrite(cur ^ 1);
        // 2) B-frag loads for this step (L2-resident)
        bf16x8 bh[4], bl[4];
#pragma unroll
        for (int n = 0; n < 4; ++n) {
            size_t bo = ((size_t)(t * 16 + wave * 4 + n) * 64 + lane) * 8;
            bh[n] = *(const bf16x8*)(Bhi + bo);
            bl[n] = *(const bf16x8*)(Blo + bo);
        }
        __builtin_amdgcn_sched_barrier(0);
        // 3) x prefetch for t+2 — issued AFTER B so B's vmcnt wait won't drain it
        if (t < NT - 2) {
            const float4* p = (const float4*)(xp + (t + 2) * BK);
            ga = p[0]; gb = p[1];
        }
        __builtin_amdgcn_sched_barrier(0);
        // 4) A frags from LDS + MFMA
        bf16x8 afr[4];
#pragma unroll
        for (int m = 0; m < 4; ++m)
            afr[m] = *(const bf16x8*)&As[cur][(m * 16 + (lane & 15)) * AROW + (lane >> 4) * 8];
#pragma unroll
        for (int n = 0; n < 4; ++n)
#pragma unroll
            for (int m = 0; m < 4; ++m) {
                acc[m][n] = __builtin_amdgcn_mfma_f32_16x16x32_bf16(afr[m], bh[n], acc[m][n], 0, 0, 0);
                acc[m][n] = __builtin_amdgcn_mfma_f32_16x16x32_bf16(afr[m], bl[n], acc[m][n], 0, 0, 0);
            }
        if (t < NT - 1) BARRIER_LGKM();
    }

    // epilogue: bias + SiLU, store h bf16, fused attention logits
    float pa[16];
#pragma unroll
    for (int i = 0; i < 16; ++i) pa[i] = 0.f;

#pragma unroll
    for (int n = 0; n < 4; ++n) {
        int col = wave * 64 + n * 16 + (lane & 15);
        float bpc = bp[col];
        float wac = Wa[col];
#pragma unroll
        for (int m = 0; m < 4; ++m) {
            size_t rowb = row0 + m * 16 + ((lane >> 4) * 4);
#pragma unroll
            for (int j = 0; j < 4; ++j) {
                float v  = acc[m][n][j] + bpc;
                float hh = v / (1.f + __expf(-v));
                h_out[(rowb + j) * NH + col] = f2bf(hh);
                pa[m * 4 + j] = fmaf(hh, wac, pa[m * 4 + j]);
            }
        }
    }
    // reduce pa over the 16 lanes sharing each row
#pragma unroll
    for (int i = 0; i < 16; ++i) {
#pragma unroll
        for (int off = 1; off < 16; off <<= 1)
            pa[i] += __shfl_xor(pa[i], off, 64);
    }
    if ((lane & 15) == 0) {
        int rg = lane >> 4;
#pragma unroll
        for (int m = 0; m < 4; ++m)
#pragma unroll
            for (int j = 0; j < 4; ++j)
                a_red[wave][m * 16 + rg * 4 + j] = pa[m * 4 + j];
    }
    __syncthreads();
    if (tid < 64) {
        float av = a_red[0][tid] + a_red[1][tid] + a_red[2][tid] + a_red[3][tid] + ba[0];
        a_out[row0 + tid] = av;
    }
}

// ---------------------------------------------------------------------------
// softmax stats, two stages: per-512-chunk (m,l) then combine
// ---------------------------------------------------------------------------
__global__ void stats1_kernel(const float* __restrict__ a, const int* __restrict__ lengths,
                              float2* __restrict__ part)
{
    __shared__ float redm[4], redl[4];
    const int b = blockIdx.y, s = blockIdx.x;
    const int len = lengths[b];
    const float* ab = a + (size_t)b * NN;
    const int tid = threadIdx.x, wave = tid >> 6, lane = tid & 63;
    const int n1 = s * 512 + tid, n2 = n1 + 256;
    const bool v1 = n1 < len, v2 = n2 < len;
    float x1 = v1 ? ab[n1] : -3e38f;
    float x2 = v2 ? ab[n2] : -3e38f;
    float m = wave_reduce_max(fmaxf(x1, x2));
    if (lane == 0) redm[wave] = m;
    __syncthreads();
    m = fmaxf(fmaxf(redm[0], redm[1]), fmaxf(redm[2], redm[3]));
    float l = (v1 ? expf(x1 - m) : 0.f) + (v2 ? expf(x2 - m) : 0.f);
    l = wave_reduce_sum(l);
    if (lane == 0) redl[wave] = l;
    __syncthreads();
    if (tid == 0) part[b * 16 + s] = float2{m, redl[0] + redl[1] + redl[2] + redl[3]};
}

__global__ void stats2_kernel(const float2* __restrict__ part, float* __restrict__ ms)
{
    int b = threadIdx.x;
    if (b < NB) {
        float m = -3e38f;
#pragma unroll
        for (int s = 0; s < 16; ++s) m = fmaxf(m, part[b * 16 + s].x);
        float l = 0.f;
#pragma unroll
        for (int s = 0; s < 16; ++s) {
            float2 p = part[b * 16 + s];
            l += p.y * expf(p.x - m);
        }
        ms[b * 2] = m;
        ms[b * 2 + 1] = l;
    }
}

// ---------------------------------------------------------------------------
// partial pooled[b, split, c] = sum_n p[n] * h[n, c]
// ---------------------------------------------------------------------------
__global__ __launch_bounds__(256)
void pool_kernel(const unsigned short* __restrict__ h, const float* __restrict__ a,
                 const int* __restrict__ lengths, const float* __restrict__ ms,
                 float* __restrict__ part)
{
    const int b = blockIdx.y;
    const int s = blockIdx.x;
    const int len = lengths[b];
    const float m     = ms[b * 2];
    const float inv_s = 1.f / ms[b * 2 + 1];

    int nbeg = s * (NN / NSPLIT);
    int nend = nbeg + (NN / NSPLIT);
    if (nend > len) nend = len;

    const float* ab = a + (size_t)b * NN;
    const unsigned short* hb = h + ((size_t)b * NN) * NH + threadIdx.x;

    float acc = 0.f;
#pragma unroll 4
    for (int n = nbeg; n < nend; ++n) {
        float p = expf(ab[n] - m);
        acc = fmaf(p, bf2f(hb[(size_t)n * NH]), acc);
    }
    part[((size_t)b * NSPLIT + s) * NH + threadIdx.x] = acc * inv_s;
}

// ---------------------------------------------------------------------------
// pooled = sum partials; logits = pooled @ Wc + bc
// ---------------------------------------------------------------------------
__global__ void final_kernel(const float* __restrict__ part, const float* __restrict__ Wc,
                             const float* __restrict__ bc, float* __restrict__ out)
{
    __shared__ float red0[4], red1[4];
    const int c = threadIdx.x;
    const float wc0 = Wc[c * NC + 0], wc1 = Wc[c * NC + 1];
    const int wave = threadIdx.x >> 6, lane = threadIdx.x & 63;

    for (int b = 0; b < NB; ++b) {
        float pooled = 0.f;
#pragma unroll 8
        for (int s = 0; s < NSPLIT; ++s)
            pooled += part[((size_t)b * NSPLIT + s) * NH + c];
        float l0 = wave_reduce_sum(pooled * wc0);
        float l1 = wave_reduce_sum(pooled * wc1);
        if (lane == 0) { red0[wave] = l0; red1[wave] = l1; }
        __syncthreads();
        if (threadIdx.x == 0) {
            out[b * NC + 0] = red0[0] + red0[1] + red0[2] + red0[3] + bc[0];
            out[b * NC + 1] = red1[0] + red1[1] + red1[2] + red1[3] + bc[1];
        }
        __syncthreads();
    }
}

extern "C" void kernel_launch(void* const* d_in, const int* in_sizes, int n_in,
                              void* d_out, int out_size, void* d_ws, size_t ws_size,
                              hipStream_t stream)
{
    const float* x       = (const float*)d_in[0];
    const int*   lengths = (const int*)d_in[1];
    const float* Wp      = (const float*)d_in[2];
    const float* bp      = (const float*)d_in[3];
    const float* Wa      = (const float*)d_in[4];
    const float* ba      = (const float*)d_in[5];
    const float* Wc      = (const float*)d_in[6];
    const float* bc      = (const float*)d_in[7];
    float* out = (float*)d_out;

    // workspace layout
    unsigned short* whi   = (unsigned short*)d_ws;            // 262144 bf16
    unsigned short* wlo   = whi + 262144;
    unsigned short* h_buf = wlo + 262144;                     // 16.7M bf16 (32 MB)
    float*  a_buf  = (float*)(h_buf + (size_t)M_ALL * NH);    // 65536 f
    float*  ms_buf = a_buf + M_ALL;                           // 16 f
    float2* spart  = (float2*)(ms_buf + 2 * NB);              // 128 float2
    float*  part   = (float*)(spart + NB * 16);               // B*64*H

    pack_kernel<<<128, 256, 0, stream>>>(Wp, whi, wlo);
    gemm_kernel<<<M_ALL / 64, 256, 0, stream>>>(x, whi, wlo, bp, Wa, ba, h_buf, a_buf);
    stats1_kernel<<<dim3(16, NB), 256, 0, stream>>>(a_buf, lengths, spart);
    stats2_kernel<<<1, 64, 0, stream>>>(spart, ms_buf);
    pool_kernel<<<dim3(NSPLIT, NB), 256, 0, stream>>>(h_buf, a_buf, lengths, ms_buf, part);
    final_kernel<<<1, 256, 0, stream>>>(part, Wc, bc, out);
}